// Round 11
// baseline (174.403 us; speedup 1.0000x reference)
//
#include <hip/hip_runtime.h>

#define B_   32
#define S_   8192
#define T_   256
#define IN_  4096
#define H_   512
#define OUT_ 10
#define CAP_ 192   // max events per (b,t) bucket; max observed ~70 (Poisson(32))
#define Q_   4     // buckets per incur block
#define FB_  16    // steps per register buffer in simfast_k
#define PADC (CAP_ + 8)

// ---------------------------------------------------------------------------
// Fused prep: z=0 transpose w_in, z=1 transpose w_rec, z=2 event scatter.
// block = (32,8)
// ---------------------------------------------------------------------------
__global__ void prep_k(const float* __restrict__ w_in, const float* __restrict__ w_rec,
                       const int4* __restrict__ x,
                       float* __restrict__ w_in_T, float* __restrict__ w_rec_T,
                       int* __restrict__ cnt, unsigned* __restrict__ data) {
    int zz = blockIdx.z;
    int tx = threadIdx.x, ty = threadIdx.y;
    if (zz == 2) {
        // ---- scatter: key = (pos<<14)|(s<<1)|val; max key per pos = last event
        int flat = blockIdx.y * gridDim.x + blockIdx.x;
        if (flat >= (B_ * S_) / 256) return;
        int e = flat * 256 + ty * 32 + tx;
        int4 ev = x[e];                       // cx, cy, val, ts
        int b = e >> 13;                      // S_ = 8192
        int s = e & (S_ - 1);
        unsigned pos = (unsigned)(ev.x * ev.y);
        unsigned key = (pos << 14) | ((unsigned)s << 1) | (unsigned)ev.z;
        int bucket = b * T_ + ev.w;
        int slot = atomicAdd(&cnt[bucket], 1);
        if (slot < CAP_) data[bucket * CAP_ + slot] = key;
        return;
    }
    // ---- transpose src[R][C] -> dst[C][R]
    const float* src = zz ? w_rec : w_in;
    float* dst = zz ? w_rec_T : w_in_T;
    const int R = H_, C = zz ? H_ : IN_;
    int bx = blockIdx.x * 32, by = blockIdx.y * 32;
    if (bx >= C || by >= R) return;
    __shared__ float tile[32][33];
    #pragma unroll
    for (int k = 0; k < 32; k += 8) {
        int r = by + ty + k, c = bx + tx;
        if (r < R && c < C) tile[ty + k][tx] = src[(size_t)r * C + c];
    }
    __syncthreads();
    #pragma unroll
    for (int k = 0; k < 32; k += 8) {
        int c = bx + ty + k, r = by + tx;
        if (c < C && r < R) dst[(size_t)c * R + r] = tile[tx][ty + k];
    }
}

// ---------------------------------------------------------------------------
// Per-bucket dedup + input-current accumulation.
// Block = 512 threads = 4 buckets x 128 threads; thread owns 4 h (float4).
// plist pre-filled with IN_ (zero row) -> gather loop has NO clamps/selects.
// ---------------------------------------------------------------------------
__global__ __launch_bounds__(512) void incur_k(const int* __restrict__ cnt,
                                               const unsigned* __restrict__ data,
                                               const float* __restrict__ w_in_T,
                                               float* __restrict__ in_cur) {
    int b  = blockIdx.x / (T_ / Q_);
    int tg = (blockIdx.x % (T_ / Q_)) * Q_;           // first t of group
    __shared__ unsigned keys[Q_][PADC];
    __shared__ unsigned char wf[Q_][PADC];
    __shared__ unsigned short plist[Q_][PADC];
    __shared__ int mq[Q_];
    int tid = threadIdx.x;
    int q = tid >> 7, lt = tid & 127;
    int bucket = b * T_ + tg + q;
    int n = cnt[bucket]; if (n > CAP_) n = CAP_;
    for (int i = lt; i < n; i += 128) keys[q][i] = data[bucket * CAP_ + i];
    #pragma unroll
    for (int i = lt; i < PADC; i += 128) plist[q][i] = (unsigned short)IN_;  // zero-row pad
    if (lt == 0) mq[q] = 0;
    __syncthreads();
    // ---- winner flags (max key per pos, val==1), batched scans (no break)
    for (int i = lt; i < n; i += 128) {
        unsigned ki = keys[q][i], pi = ki >> 14;
        bool dead = false;
        for (int j = 0; j < n; j += 4) {
            unsigned a0 = keys[q][j];
            unsigned a1 = keys[q][j + 1 < n ? j + 1 : 0];
            unsigned a2 = keys[q][j + 2 < n ? j + 2 : 0];
            unsigned a3 = keys[q][j + 3 < n ? j + 3 : 0];
            dead |= (((a0 >> 14) == pi) & (a0 > ki));
            dead |= ((j + 1 < n) & ((a1 >> 14) == pi) & (a1 > ki));
            dead |= ((j + 2 < n) & ((a2 >> 14) == pi) & (a2 > ki));
            dead |= ((j + 3 < n) & ((a3 >> 14) == pi) & (a3 > ki));
        }
        wf[q][i] = (unsigned char)(((ki & 1u) != 0u) && !dead);
    }
    __syncthreads();
    // ---- rank by ascending key (winners have distinct pos) + compact
    for (int i = lt; i < n; i += 128) {
        if (wf[q][i]) {
            unsigned ki = keys[q][i];
            int r = 0;
            for (int j = 0; j < n; j += 4) {
                r += (int)(wf[q][j] && keys[q][j] < ki);
                r += (int)((j + 1 < n) && wf[q][j + 1] && keys[q][j + 1] < ki);
                r += (int)((j + 2 < n) && wf[q][j + 2] && keys[q][j + 2] < ki);
                r += (int)((j + 3 < n) && wf[q][j + 3] && keys[q][j + 3] < ki);
            }
            plist[q][r] = (unsigned short)(ki >> 14);
            atomicAdd(&mq[q], 1);
        }
    }
    __syncthreads();                                  // plist + mq ready
    // ---- gather: thread sums rows for h = lt*4 .. lt*4+3 (float4)
    int m = mq[q];
    const float4* w4 = (const float4*)w_in_T;         // [IN_+1][128]
    float4 acc = make_float4(0.f, 0.f, 0.f, 0.f);
    for (int k = 0; k < m; k += 4) {                  // pads read the zero row
        float4 g0 = w4[(size_t)plist[q][k + 0] * 128 + lt];
        float4 g1 = w4[(size_t)plist[q][k + 1] * 128 + lt];
        float4 g2 = w4[(size_t)plist[q][k + 2] * 128 + lt];
        float4 g3 = w4[(size_t)plist[q][k + 3] * 128 + lt];
        acc.x = (((acc.x + g0.x) + g1.x) + g2.x) + g3.x;
        acc.y = (((acc.y + g0.y) + g1.y) + g2.y) + g3.y;
        acc.z = (((acc.z + g0.z) + g1.z) + g2.z) + g3.z;
        acc.w = (((acc.w + g0.w) + g1.w) + g2.w) + g3.w;
    }
    ((float4*)(in_cur + (size_t)(tg + q) * (B_ * H_) + b * H_))[lt] = acc;
}

// ---------------------------------------------------------------------------
// Fast spike scan: 256 blocks x 64 threads (one wave per CU chip-wide).
// Thread = unit (b, h). Walks the no-reset trajectory (bit-identical to the
// true one up to the first crossing) and records the EXACT first step where
// vd > 0.5 via atomicMin(tfirst[b]). Zero-fills out.
// ---------------------------------------------------------------------------
__global__ __launch_bounds__(64) void simfast_k(const float* __restrict__ in_cur,
                                                unsigned* __restrict__ tfirst,
                                                float* __restrict__ out) {
    int blk = blockIdx.x;              // B_*8 blocks
    int b = blk >> 3;
    int slice = blk & 7;
    int tid = threadIdx.x;

    // zero this block's out slice: t in [slice*32, slice*32+32), 10 outs
    #pragma unroll
    for (int i = tid; i < 320; i += 64) {
        int t = (slice << 5) + i / 10;
        int o = i - (i / 10) * 10;
        out[(size_t)t * (B_ * OUT_) + b * OUT_ + o] = 0.f;
    }

    int h = (slice << 6) + tid;
    const float* p = in_cur + b * H_ + h;
    float v = 0.f, cur = 0.f;
    int tc = T_;                       // first crossing step (T_ = none)
    float buf0[FB_], buf1[FB_];
    #pragma unroll
    for (int s = 0; s < FB_; ++s) buf0[s] = p[(size_t)s * (B_ * H_)];
    #pragma unroll
    for (int s = 0; s < FB_; ++s) buf1[s] = p[(size_t)(FB_ + s) * (B_ * H_)];

    for (int t0 = 0; t0 < T_; t0 += 2 * FB_) {
        #pragma unroll
        for (int s = 0; s < FB_; ++s) {
            float vd = fmaf(0.1f, cur - v, v);
            tc = (vd > 0.5f && tc == T_) ? (t0 + s) : tc;
            v = vd;
            cur = cur * 0.8f + buf0[s];
        }
        if (t0 + 2 * FB_ < T_) {
            #pragma unroll
            for (int s = 0; s < FB_; ++s)
                buf0[s] = p[(size_t)(t0 + 2 * FB_ + s) * (B_ * H_)];
        }
        #pragma unroll
        for (int s = 0; s < FB_; ++s) {
            float vd = fmaf(0.1f, cur - v, v);
            tc = (vd > 0.5f && tc == T_) ? (t0 + FB_ + s) : tc;
            v = vd;
            cur = cur * 0.8f + buf1[s];
        }
        if (t0 + 3 * FB_ < T_) {
            #pragma unroll
            for (int s = 0; s < FB_; ++s)
                buf1[s] = p[(size_t)(t0 + 3 * FB_ + s) * (B_ * H_)];
        }
    }
    if (tc < T_) atomicMin(&tfirst[b], (unsigned)tc);
}

// ---------------------------------------------------------------------------
// Exact completion for batches with a crossing (tfirst[b] < T_).
// Phase 1 [0, tf): pure per-thread recurrence; inputs in 16 NAMED scalars
// (no arrays -> no scratch). No spikes before tf => vo = io = 0 analytically.
// Phase 2 [tf, T_): exact per-step ballot/LDS machinery, z_prev timing:
// i_new = i_dec + input + z_prev @ w_rec.T ; y = z_new @ w_out.T.
// ---------------------------------------------------------------------------
__global__ __launch_bounds__(512) void simfb_k(const unsigned* __restrict__ tfirst,
                                               const float* __restrict__ in_cur,
                                               const float* __restrict__ w_rec_T,
                                               const float* __restrict__ w_out,
                                               float* __restrict__ out) {
    int b = blockIdx.x;
    unsigned tfu = tfirst[b];
    if (tfu >= (unsigned)T_) return;       // uniform early exit (before barriers)
    int tf = (int)tfu;
    int tid = threadIdx.x, wid = tid >> 6, lane = tid & 63;
    __shared__ unsigned long long mword[2][8];
    const size_t BH = B_ * H_;
    const float* icb = in_cur + b * H_ + tid;
    float* outp = out + b * OUT_ + tid;    // valid when tid < OUT_
    float v = 0.f, cur = 0.f;

#define PSTEP(X) { float vd_ = fmaf(0.1f, cur - v, v); v = vd_; cur = cur * 0.8f + (X); }
    // ---- phase 1: t in [0, tf), chunked 16 named-scalar loads
    for (int t = 0; t < tf; t += 16) {
        float i0  = icb[(size_t)min(t + 0,  T_ - 1) * BH];
        float i1  = icb[(size_t)min(t + 1,  T_ - 1) * BH];
        float i2  = icb[(size_t)min(t + 2,  T_ - 1) * BH];
        float i3  = icb[(size_t)min(t + 3,  T_ - 1) * BH];
        float i4  = icb[(size_t)min(t + 4,  T_ - 1) * BH];
        float i5  = icb[(size_t)min(t + 5,  T_ - 1) * BH];
        float i6  = icb[(size_t)min(t + 6,  T_ - 1) * BH];
        float i7  = icb[(size_t)min(t + 7,  T_ - 1) * BH];
        float i8  = icb[(size_t)min(t + 8,  T_ - 1) * BH];
        float i9  = icb[(size_t)min(t + 9,  T_ - 1) * BH];
        float i10 = icb[(size_t)min(t + 10, T_ - 1) * BH];
        float i11 = icb[(size_t)min(t + 11, T_ - 1) * BH];
        float i12 = icb[(size_t)min(t + 12, T_ - 1) * BH];
        float i13 = icb[(size_t)min(t + 13, T_ - 1) * BH];
        float i14 = icb[(size_t)min(t + 14, T_ - 1) * BH];
        float i15 = icb[(size_t)min(t + 15, T_ - 1) * BH];
        if (t + 16 <= tf) {                // full chunk, unconditional
            PSTEP(i0)  PSTEP(i1)  PSTEP(i2)  PSTEP(i3)
            PSTEP(i4)  PSTEP(i5)  PSTEP(i6)  PSTEP(i7)
            PSTEP(i8)  PSTEP(i9)  PSTEP(i10) PSTEP(i11)
            PSTEP(i12) PSTEP(i13) PSTEP(i14) PSTEP(i15)
        } else {                           // tail: wave-uniform predicated
            if (t + 0  < tf) PSTEP(i0)   if (t + 1  < tf) PSTEP(i1)
            if (t + 2  < tf) PSTEP(i2)   if (t + 3  < tf) PSTEP(i3)
            if (t + 4  < tf) PSTEP(i4)   if (t + 5  < tf) PSTEP(i5)
            if (t + 6  < tf) PSTEP(i6)   if (t + 7  < tf) PSTEP(i7)
            if (t + 8  < tf) PSTEP(i8)   if (t + 9  < tf) PSTEP(i9)
            if (t + 10 < tf) PSTEP(i10)  if (t + 11 < tf) PSTEP(i11)
            if (t + 12 < tf) PSTEP(i12)  if (t + 13 < tf) PSTEP(i13)
            if (t + 14 < tf) PSTEP(i14)  if (t + 15 < tf) PSTEP(i15)
        }
    }
#undef PSTEP

    // ---- phase 2: t in [tf, T_), exact machinery. vo = io = 0 at entry.
    float vo = 0.f, io = 0.f;
    if (tid < 16) ((unsigned long long*)mword)[tid] = 0ULL;  // no prev spikes
    __syncthreads();
    for (int t = tf; t < T_; ++t) {
        int p = t & 1;
        float inc = icb[(size_t)t * BH];
        float vd = fmaf(0.1f, cur - v, v);
        bool z = vd > 0.5f;
        v = z ? 0.f : vd;
        unsigned long long bal = __ballot(z);
        if (lane == 0) mword[p][wid] = bal;
        __syncthreads();
        float c2 = cur * 0.8f + inc;       // i_dec + input first
        for (int w = 0; w < 8; ++w) {      // + z_prev @ w_rec.T, ascending j
            unsigned long long mm = mword[p ^ 1][w];
            while (mm) {
                int j = __builtin_ctzll(mm);
                c2 += w_rec_T[(size_t)((w << 6) + j) * H_ + tid];
                mm &= mm - 1;
            }
        }
        cur = c2;
        if (tid < OUT_) {
            float y = 0.f;
            for (int w = 0; w < 8; ++w) {  // z_new @ w_out.T
                unsigned long long mm = mword[p][w];
                while (mm) {
                    int j = __builtin_ctzll(mm);
                    y += w_out[tid * H_ + (w << 6) + j];
                    mm &= mm - 1;
                }
            }
            float von = fmaf(0.1f, io - vo, vo);   // uses OLD io
            io = io * 0.8f + y;
            outp[(size_t)t * (B_ * OUT_)] = von;
            vo = von;
        }
        __syncthreads();                   // protect mword reuse
    }
}

// ---------------------------------------------------------------------------
extern "C" void kernel_launch(void* const* d_in, const int* in_sizes, int n_in,
                              void* d_out, int out_size, void* d_ws, size_t ws_size,
                              hipStream_t stream) {
    const int*   x     = (const int*)d_in[0];
    const float* w_in  = (const float*)d_in[1];
    const float* w_rec = (const float*)d_in[2];
    const float* w_out = (const float*)d_in[3];
    float* out = (float*)d_out;

    char* ws = (char*)d_ws;
    size_t off = 0;
    int*      cnt     = (int*)(ws + off);      off += (size_t)B_ * T_ * 4;            // 32 KB
    unsigned* tfirst  = (unsigned*)(ws + off); off += (size_t)B_ * 4;                 // 128 B
    unsigned* data    = (unsigned*)(ws + off); off += (size_t)B_ * T_ * CAP_ * 4;     // 6 MB
    float*    w_in_T  = (float*)(ws + off);    off += (size_t)(IN_ + 1) * H_ * 4;     // 8 MB + zero row
    float*    w_rec_T = (float*)(ws + off);    off += (size_t)H_ * H_ * 4;            // 1 MB
    float*    in_cur  = (float*)(ws + off);    off += (size_t)T_ * B_ * H_ * 4;       // 16 MB

    (void)hipMemsetAsync(cnt, 0, (size_t)B_ * T_ * 4, stream);
    (void)hipMemsetAsync(tfirst, 0xFF, (size_t)B_ * 4, stream);          // = huge
    (void)hipMemsetAsync(w_in_T + (size_t)IN_ * H_, 0, H_ * 4, stream);  // zero pad row

    // z=0: w_in transpose (128x16 tiles); z=1: w_rec (16x16); z=2: scatter (1024 blocks)
    prep_k<<<dim3(128, 16, 3), dim3(32, 8), 0, stream>>>(w_in, w_rec, (const int4*)x,
                                                         w_in_T, w_rec_T, cnt, data);

    incur_k<<<B_ * (T_ / Q_), 512, 0, stream>>>(cnt, data, w_in_T, in_cur);

    simfast_k<<<B_ * 8, 64, 0, stream>>>(in_cur, tfirst, out);

    simfb_k<<<B_, 512, 0, stream>>>(tfirst, in_cur, w_rec_T, w_out, out);
}

// Round 12
// 169.867 us; speedup vs baseline: 1.0267x; 1.0267x over previous
//
#include <hip/hip_runtime.h>

#define B_   32
#define S_   8192
#define T_   256
#define IN_  4096
#define H_   512
#define OUT_ 10
#define CAP_ 192   // max events per (b,t) bucket; max observed ~70 (Poisson(32))
#define Q_   4     // buckets per incur block
#define FB_  16    // steps per register buffer in simfast_k
#define PADC (CAP_ + 8)

// ---------------------------------------------------------------------------
// Fused prep: z=0 transpose w_in, z=1 transpose w_rec, z=2 event scatter.
// block = (32,8)
// ---------------------------------------------------------------------------
__global__ void prep_k(const float* __restrict__ w_in, const float* __restrict__ w_rec,
                       const int4* __restrict__ x,
                       float* __restrict__ w_in_T, float* __restrict__ w_rec_T,
                       int* __restrict__ cnt, unsigned* __restrict__ data) {
    int zz = blockIdx.z;
    int tx = threadIdx.x, ty = threadIdx.y;
    if (zz == 2) {
        // ---- scatter: key = (pos<<14)|(s<<1)|val; max key per pos = last event
        int flat = blockIdx.y * gridDim.x + blockIdx.x;
        if (flat >= (B_ * S_) / 256) return;
        int e = flat * 256 + ty * 32 + tx;
        int4 ev = x[e];                       // cx, cy, val, ts
        int b = e >> 13;                      // S_ = 8192
        int s = e & (S_ - 1);
        unsigned pos = (unsigned)(ev.x * ev.y);
        unsigned key = (pos << 14) | ((unsigned)s << 1) | (unsigned)ev.z;
        int bucket = b * T_ + ev.w;
        int slot = atomicAdd(&cnt[bucket], 1);
        if (slot < CAP_) data[bucket * CAP_ + slot] = key;
        return;
    }
    // ---- transpose src[R][C] -> dst[C][R]
    const float* src = zz ? w_rec : w_in;
    float* dst = zz ? w_rec_T : w_in_T;
    const int R = H_, C = zz ? H_ : IN_;
    int bx = blockIdx.x * 32, by = blockIdx.y * 32;
    if (bx >= C || by >= R) return;
    __shared__ float tile[32][33];
    #pragma unroll
    for (int k = 0; k < 32; k += 8) {
        int r = by + ty + k, c = bx + tx;
        if (r < R && c < C) tile[ty + k][tx] = src[(size_t)r * C + c];
    }
    __syncthreads();
    #pragma unroll
    for (int k = 0; k < 32; k += 8) {
        int c = bx + ty + k, r = by + tx;
        if (c < C && r < R) dst[(size_t)c * R + r] = tile[tx][ty + k];
    }
}

// ---------------------------------------------------------------------------
// Per-bucket dedup + input-current accumulation.
// Block = 512 threads = 4 buckets x 128 threads; thread owns 4 h (float4).
// plist pre-filled with IN_ (zero row) -> gather loop has NO clamps/selects.
// ---------------------------------------------------------------------------
__global__ __launch_bounds__(512) void incur_k(const int* __restrict__ cnt,
                                               const unsigned* __restrict__ data,
                                               const float* __restrict__ w_in_T,
                                               float* __restrict__ in_cur) {
    int b  = blockIdx.x / (T_ / Q_);
    int tg = (blockIdx.x % (T_ / Q_)) * Q_;           // first t of group
    __shared__ unsigned keys[Q_][PADC];
    __shared__ unsigned char wf[Q_][PADC];
    __shared__ unsigned short plist[Q_][PADC];
    __shared__ int mq[Q_];
    int tid = threadIdx.x;
    int q = tid >> 7, lt = tid & 127;
    int bucket = b * T_ + tg + q;
    int n = cnt[bucket]; if (n > CAP_) n = CAP_;
    for (int i = lt; i < n; i += 128) keys[q][i] = data[bucket * CAP_ + i];
    #pragma unroll
    for (int i = lt; i < PADC; i += 128) plist[q][i] = (unsigned short)IN_;  // zero-row pad
    if (lt == 0) mq[q] = 0;
    __syncthreads();
    // ---- winner flags (max key per pos, val==1), batched scans (no break)
    for (int i = lt; i < n; i += 128) {
        unsigned ki = keys[q][i], pi = ki >> 14;
        bool dead = false;
        for (int j = 0; j < n; j += 4) {
            unsigned a0 = keys[q][j];
            unsigned a1 = keys[q][j + 1 < n ? j + 1 : 0];
            unsigned a2 = keys[q][j + 2 < n ? j + 2 : 0];
            unsigned a3 = keys[q][j + 3 < n ? j + 3 : 0];
            dead |= (((a0 >> 14) == pi) & (a0 > ki));
            dead |= ((j + 1 < n) & ((a1 >> 14) == pi) & (a1 > ki));
            dead |= ((j + 2 < n) & ((a2 >> 14) == pi) & (a2 > ki));
            dead |= ((j + 3 < n) & ((a3 >> 14) == pi) & (a3 > ki));
        }
        wf[q][i] = (unsigned char)(((ki & 1u) != 0u) && !dead);
    }
    __syncthreads();
    // ---- rank by ascending key (winners have distinct pos) + compact
    for (int i = lt; i < n; i += 128) {
        if (wf[q][i]) {
            unsigned ki = keys[q][i];
            int r = 0;
            for (int j = 0; j < n; j += 4) {
                r += (int)(wf[q][j] && keys[q][j] < ki);
                r += (int)((j + 1 < n) && wf[q][j + 1] && keys[q][j + 1] < ki);
                r += (int)((j + 2 < n) && wf[q][j + 2] && keys[q][j + 2] < ki);
                r += (int)((j + 3 < n) && wf[q][j + 3] && keys[q][j + 3] < ki);
            }
            plist[q][r] = (unsigned short)(ki >> 14);
            atomicAdd(&mq[q], 1);
        }
    }
    __syncthreads();                                  // plist + mq ready
    // ---- gather: thread sums rows for h = lt*4 .. lt*4+3 (float4)
    int m = mq[q];
    const float4* w4 = (const float4*)w_in_T;         // [IN_+1][128]
    float4 acc = make_float4(0.f, 0.f, 0.f, 0.f);
    for (int k = 0; k < m; k += 4) {                  // pads read the zero row
        float4 g0 = w4[(size_t)plist[q][k + 0] * 128 + lt];
        float4 g1 = w4[(size_t)plist[q][k + 1] * 128 + lt];
        float4 g2 = w4[(size_t)plist[q][k + 2] * 128 + lt];
        float4 g3 = w4[(size_t)plist[q][k + 3] * 128 + lt];
        acc.x = (((acc.x + g0.x) + g1.x) + g2.x) + g3.x;
        acc.y = (((acc.y + g0.y) + g1.y) + g2.y) + g3.y;
        acc.z = (((acc.z + g0.z) + g1.z) + g2.z) + g3.z;
        acc.w = (((acc.w + g0.w) + g1.w) + g2.w) + g3.w;
    }
    ((float4*)(in_cur + (size_t)(tg + q) * (B_ * H_) + b * H_))[lt] = acc;
}

// ---------------------------------------------------------------------------
// Fast spike scan: 256 blocks x 64 threads (one wave per CU chip-wide).
// Thread = unit (b, h). Walks the no-reset trajectory (bit-identical to the
// true one up to the first crossing), records the EXACT first crossing step
// via atomicMin(tfirst[b]), checkpoints (v, cur) every 8 steps (state at the
// START of step t, exact for all t <= first crossing), zero-fills out.
// ---------------------------------------------------------------------------
__global__ __launch_bounds__(64) void simfast_k(const float* __restrict__ in_cur,
                                                unsigned* __restrict__ tfirst,
                                                float2* __restrict__ ckpt,
                                                float* __restrict__ out) {
    int blk = blockIdx.x;              // B_*8 blocks
    int b = blk >> 3;
    int slice = blk & 7;
    int tid = threadIdx.x;

    // zero this block's out slice: t in [slice*32, slice*32+32), 10 outs
    #pragma unroll
    for (int i = tid; i < 320; i += 64) {
        int t = (slice << 5) + i / 10;
        int o = i - (i / 10) * 10;
        out[(size_t)t * (B_ * OUT_) + b * OUT_ + o] = 0.f;
    }

    int h = (slice << 6) + tid;
    const float* p = in_cur + b * H_ + h;
    float2* ckb = ckpt + b * H_ + h;   // [T_/8][B_][H_] layout
    float v = 0.f, cur = 0.f;
    int tc = T_;                       // first crossing step (T_ = none)
    float buf0[FB_], buf1[FB_];
    #pragma unroll
    for (int s = 0; s < FB_; ++s) buf0[s] = p[(size_t)s * (B_ * H_)];
    #pragma unroll
    for (int s = 0; s < FB_; ++s) buf1[s] = p[(size_t)(FB_ + s) * (B_ * H_)];

    for (int t0 = 0; t0 < T_; t0 += 2 * FB_) {
        #pragma unroll
        for (int s = 0; s < FB_; ++s) {
            if ((s & 7) == 0)          // static (unrolled): checkpoint @ t0+s
                ckb[(size_t)((t0 + s) >> 3) * (B_ * H_)] = make_float2(v, cur);
            float vd = fmaf(0.1f, cur - v, v);
            tc = (vd > 0.5f && tc == T_) ? (t0 + s) : tc;
            v = vd;
            cur = cur * 0.8f + buf0[s];
        }
        if (t0 + 2 * FB_ < T_) {
            #pragma unroll
            for (int s = 0; s < FB_; ++s)
                buf0[s] = p[(size_t)(t0 + 2 * FB_ + s) * (B_ * H_)];
        }
        #pragma unroll
        for (int s = 0; s < FB_; ++s) {
            if ((s & 7) == 0)          // checkpoint @ t0+FB_+s
                ckb[(size_t)((t0 + FB_ + s) >> 3) * (B_ * H_)] = make_float2(v, cur);
            float vd = fmaf(0.1f, cur - v, v);
            tc = (vd > 0.5f && tc == T_) ? (t0 + FB_ + s) : tc;
            v = vd;
            cur = cur * 0.8f + buf1[s];
        }
        if (t0 + 3 * FB_ < T_) {
            #pragma unroll
            for (int s = 0; s < FB_; ++s)
                buf1[s] = p[(size_t)(t0 + 3 * FB_ + s) * (B_ * H_)];
        }
    }
    if (tc < T_) atomicMin(&tfirst[b], (unsigned)tc);
}

// ---------------------------------------------------------------------------
// Exact completion for batches with a crossing (tfirst[b] < T_).
// Resume from checkpoint at c0 = tf & ~7 (exact state, <= 7 serial steps to
// tf), then exact per-step ballot/LDS machinery for [tf, T_):
// i_new = i_dec + input + z_prev @ w_rec.T ; y = z_new @ w_out.T.
// vo = io = 0 at entry (no output spikes before tf).
// ---------------------------------------------------------------------------
__global__ __launch_bounds__(512) void simfb_k(const unsigned* __restrict__ tfirst,
                                               const float* __restrict__ in_cur,
                                               const float2* __restrict__ ckpt,
                                               const float* __restrict__ w_rec_T,
                                               const float* __restrict__ w_out,
                                               float* __restrict__ out) {
    int b = blockIdx.x;
    unsigned tfu = tfirst[b];
    if (tfu >= (unsigned)T_) return;       // uniform early exit (before barriers)
    int tf = (int)tfu;
    int tid = threadIdx.x, wid = tid >> 6, lane = tid & 63;
    __shared__ unsigned long long mword[2][8];
    const size_t BH = B_ * H_;
    const float* icb = in_cur + b * H_ + tid;
    float* outp = out + b * OUT_ + tid;    // valid when tid < OUT_

    // ---- resume from checkpoint
    int c0 = tf & ~7;
    float2 st = ckpt[(size_t)(c0 >> 3) * BH + b * H_ + tid];
    float v = st.x, cur = st.y;
    for (int t = c0; t < tf; ++t) {        // <= 7 serial steps
        float inc = icb[(size_t)t * BH];
        float vd = fmaf(0.1f, cur - v, v);
        v = vd;
        cur = cur * 0.8f + inc;
    }

    // ---- exact machinery for [tf, T_). vo = io = 0 at entry.
    float vo = 0.f, io = 0.f;
    if (tid < 16) ((unsigned long long*)mword)[tid] = 0ULL;  // no prev spikes
    __syncthreads();
    for (int t = tf; t < T_; ++t) {
        int p = t & 1;
        float inc = icb[(size_t)t * BH];
        float vd = fmaf(0.1f, cur - v, v);
        bool z = vd > 0.5f;
        v = z ? 0.f : vd;
        unsigned long long bal = __ballot(z);
        if (lane == 0) mword[p][wid] = bal;
        __syncthreads();
        float c2 = cur * 0.8f + inc;       // i_dec + input first
        for (int w = 0; w < 8; ++w) {      // + z_prev @ w_rec.T, ascending j
            unsigned long long mm = mword[p ^ 1][w];
            while (mm) {
                int j = __builtin_ctzll(mm);
                c2 += w_rec_T[(size_t)((w << 6) + j) * H_ + tid];
                mm &= mm - 1;
            }
        }
        cur = c2;
        if (tid < OUT_) {
            float y = 0.f;
            for (int w = 0; w < 8; ++w) {  // z_new @ w_out.T
                unsigned long long mm = mword[p][w];
                while (mm) {
                    int j = __builtin_ctzll(mm);
                    y += w_out[tid * H_ + (w << 6) + j];
                    mm &= mm - 1;
                }
            }
            float von = fmaf(0.1f, io - vo, vo);   // uses OLD io
            io = io * 0.8f + y;
            outp[(size_t)t * (B_ * OUT_)] = von;
            vo = von;
        }
        __syncthreads();                   // protect mword reuse
    }
}

// ---------------------------------------------------------------------------
extern "C" void kernel_launch(void* const* d_in, const int* in_sizes, int n_in,
                              void* d_out, int out_size, void* d_ws, size_t ws_size,
                              hipStream_t stream) {
    const int*   x     = (const int*)d_in[0];
    const float* w_in  = (const float*)d_in[1];
    const float* w_rec = (const float*)d_in[2];
    const float* w_out = (const float*)d_in[3];
    float* out = (float*)d_out;

    char* ws = (char*)d_ws;
    size_t off = 0;
    int*      cnt     = (int*)(ws + off);      off += (size_t)B_ * T_ * 4;            // 32 KB
    unsigned* tfirst  = (unsigned*)(ws + off); off += (size_t)B_ * 4;                 // 128 B
    unsigned* data    = (unsigned*)(ws + off); off += (size_t)B_ * T_ * CAP_ * 4;     // 6 MB
    float*    w_in_T  = (float*)(ws + off);    off += (size_t)(IN_ + 1) * H_ * 4;     // 8 MB + zero row
    float*    w_rec_T = (float*)(ws + off);    off += (size_t)H_ * H_ * 4;            // 1 MB
    float*    in_cur  = (float*)(ws + off);    off += (size_t)T_ * B_ * H_ * 4;       // 16 MB
    float2*   ckpt    = (float2*)(ws + off);   off += (size_t)(T_ / 8) * B_ * H_ * 8; // 4 MB

    (void)hipMemsetAsync(cnt, 0, (size_t)B_ * T_ * 4, stream);
    (void)hipMemsetAsync(tfirst, 0xFF, (size_t)B_ * 4, stream);          // = huge
    (void)hipMemsetAsync(w_in_T + (size_t)IN_ * H_, 0, H_ * 4, stream);  // zero pad row

    // z=0: w_in transpose (128x16 tiles); z=1: w_rec (16x16); z=2: scatter (1024 blocks)
    prep_k<<<dim3(128, 16, 3), dim3(32, 8), 0, stream>>>(w_in, w_rec, (const int4*)x,
                                                         w_in_T, w_rec_T, cnt, data);

    incur_k<<<B_ * (T_ / Q_), 512, 0, stream>>>(cnt, data, w_in_T, in_cur);

    simfast_k<<<B_ * 8, 64, 0, stream>>>(in_cur, tfirst, ckpt, out);

    simfb_k<<<B_, 512, 0, stream>>>(tfirst, in_cur, ckpt, w_rec_T, w_out, out);
}

// Round 13
// 159.355 us; speedup vs baseline: 1.0944x; 1.0660x over previous
//
#include <hip/hip_runtime.h>

#define B_   32
#define S_   8192
#define T_   256
#define IN_  4096
#define H_   512
#define OUT_ 10
#define CAP_ 192   // max events per (b,t) bucket; max observed ~70 (Poisson(32))
#define Q_   4     // buckets per incur block
#define FB_  16    // steps per register buffer in simfast_k
#define PADC (CAP_ + 8)

// ---------------------------------------------------------------------------
// Fused prep: z=0 transpose w_in, z=1 transpose w_rec, z=2 event scatter.
// block = (32,8)
// ---------------------------------------------------------------------------
__global__ void prep_k(const float* __restrict__ w_in, const float* __restrict__ w_rec,
                       const int4* __restrict__ x,
                       float* __restrict__ w_in_T, float* __restrict__ w_rec_T,
                       int* __restrict__ cnt, unsigned* __restrict__ data) {
    int zz = blockIdx.z;
    int tx = threadIdx.x, ty = threadIdx.y;
    if (zz == 2) {
        // ---- scatter: key = (pos<<14)|(s<<1)|val; max key per pos = last event
        int flat = blockIdx.y * gridDim.x + blockIdx.x;
        if (flat >= (B_ * S_) / 256) return;
        int e = flat * 256 + ty * 32 + tx;
        int4 ev = x[e];                       // cx, cy, val, ts
        int b = e >> 13;                      // S_ = 8192
        int s = e & (S_ - 1);
        unsigned pos = (unsigned)(ev.x * ev.y);
        unsigned key = (pos << 14) | ((unsigned)s << 1) | (unsigned)ev.z;
        int bucket = b * T_ + ev.w;
        int slot = atomicAdd(&cnt[bucket], 1);
        if (slot < CAP_) data[bucket * CAP_ + slot] = key;
        return;
    }
    // ---- transpose src[R][C] -> dst[C][R]
    const float* src = zz ? w_rec : w_in;
    float* dst = zz ? w_rec_T : w_in_T;
    const int R = H_, C = zz ? H_ : IN_;
    int bx = blockIdx.x * 32, by = blockIdx.y * 32;
    if (bx >= C || by >= R) return;
    __shared__ float tile[32][33];
    #pragma unroll
    for (int k = 0; k < 32; k += 8) {
        int r = by + ty + k, c = bx + tx;
        if (r < R && c < C) tile[ty + k][tx] = src[(size_t)r * C + c];
    }
    __syncthreads();
    #pragma unroll
    for (int k = 0; k < 32; k += 8) {
        int c = bx + ty + k, r = by + tx;
        if (c < C && r < R) dst[(size_t)c * R + r] = tile[tx][ty + k];
    }
}

// ---------------------------------------------------------------------------
// Per-bucket dedup + input-current accumulation.
// Block = 512 threads = 4 buckets x 128 threads; thread owns 4 h (float4).
// plist pre-filled with IN_ (zero row) -> gather loop has NO clamps/selects.
// ---------------------------------------------------------------------------
__global__ __launch_bounds__(512) void incur_k(const int* __restrict__ cnt,
                                               const unsigned* __restrict__ data,
                                               const float* __restrict__ w_in_T,
                                               float* __restrict__ in_cur) {
    int b  = blockIdx.x / (T_ / Q_);
    int tg = (blockIdx.x % (T_ / Q_)) * Q_;           // first t of group
    __shared__ unsigned keys[Q_][PADC];
    __shared__ unsigned char wf[Q_][PADC];
    __shared__ unsigned short plist[Q_][PADC];
    __shared__ int mq[Q_];
    int tid = threadIdx.x;
    int q = tid >> 7, lt = tid & 127;
    int bucket = b * T_ + tg + q;
    int n = cnt[bucket]; if (n > CAP_) n = CAP_;
    for (int i = lt; i < n; i += 128) keys[q][i] = data[bucket * CAP_ + i];
    #pragma unroll
    for (int i = lt; i < PADC; i += 128) plist[q][i] = (unsigned short)IN_;  // zero-row pad
    if (lt == 0) mq[q] = 0;
    __syncthreads();
    // ---- winner flags (max key per pos, val==1), batched scans (no break)
    for (int i = lt; i < n; i += 128) {
        unsigned ki = keys[q][i], pi = ki >> 14;
        bool dead = false;
        for (int j = 0; j < n; j += 4) {
            unsigned a0 = keys[q][j];
            unsigned a1 = keys[q][j + 1 < n ? j + 1 : 0];
            unsigned a2 = keys[q][j + 2 < n ? j + 2 : 0];
            unsigned a3 = keys[q][j + 3 < n ? j + 3 : 0];
            dead |= (((a0 >> 14) == pi) & (a0 > ki));
            dead |= ((j + 1 < n) & ((a1 >> 14) == pi) & (a1 > ki));
            dead |= ((j + 2 < n) & ((a2 >> 14) == pi) & (a2 > ki));
            dead |= ((j + 3 < n) & ((a3 >> 14) == pi) & (a3 > ki));
        }
        wf[q][i] = (unsigned char)(((ki & 1u) != 0u) && !dead);
    }
    __syncthreads();
    // ---- rank by ascending key (winners have distinct pos) + compact
    for (int i = lt; i < n; i += 128) {
        if (wf[q][i]) {
            unsigned ki = keys[q][i];
            int r = 0;
            for (int j = 0; j < n; j += 4) {
                r += (int)(wf[q][j] && keys[q][j] < ki);
                r += (int)((j + 1 < n) && wf[q][j + 1] && keys[q][j + 1] < ki);
                r += (int)((j + 2 < n) && wf[q][j + 2] && keys[q][j + 2] < ki);
                r += (int)((j + 3 < n) && wf[q][j + 3] && keys[q][j + 3] < ki);
            }
            plist[q][r] = (unsigned short)(ki >> 14);
            atomicAdd(&mq[q], 1);
        }
    }
    __syncthreads();                                  // plist + mq ready
    // ---- gather: thread sums rows for h = lt*4 .. lt*4+3 (float4)
    int m = mq[q];
    const float4* w4 = (const float4*)w_in_T;         // [IN_+1][128]
    float4 acc = make_float4(0.f, 0.f, 0.f, 0.f);
    for (int k = 0; k < m; k += 4) {                  // pads read the zero row
        float4 g0 = w4[(size_t)plist[q][k + 0] * 128 + lt];
        float4 g1 = w4[(size_t)plist[q][k + 1] * 128 + lt];
        float4 g2 = w4[(size_t)plist[q][k + 2] * 128 + lt];
        float4 g3 = w4[(size_t)plist[q][k + 3] * 128 + lt];
        acc.x = (((acc.x + g0.x) + g1.x) + g2.x) + g3.x;
        acc.y = (((acc.y + g0.y) + g1.y) + g2.y) + g3.y;
        acc.z = (((acc.z + g0.z) + g1.z) + g2.z) + g3.z;
        acc.w = (((acc.w + g0.w) + g1.w) + g2.w) + g3.w;
    }
    ((float4*)(in_cur + (size_t)(tg + q) * (B_ * H_) + b * H_))[lt] = acc;
}

// ---------------------------------------------------------------------------
// Fast spike scan: 256 blocks x 64 threads (one wave per CU chip-wide).
// Thread = unit (b, h). Walks the no-reset trajectory (bit-identical to the
// true one up to the first crossing), records the EXACT first crossing step
// via atomicMin(tfirst[b]), checkpoints (v, cur) every 8 steps (state at the
// START of step t, exact for all t <= first crossing), zero-fills out.
// ---------------------------------------------------------------------------
__global__ __launch_bounds__(64) void simfast_k(const float* __restrict__ in_cur,
                                                unsigned* __restrict__ tfirst,
                                                float2* __restrict__ ckpt,
                                                float* __restrict__ out) {
    int blk = blockIdx.x;              // B_*8 blocks
    int b = blk >> 3;
    int slice = blk & 7;
    int tid = threadIdx.x;

    // zero this block's out slice: t in [slice*32, slice*32+32), 10 outs
    #pragma unroll
    for (int i = tid; i < 320; i += 64) {
        int t = (slice << 5) + i / 10;
        int o = i - (i / 10) * 10;
        out[(size_t)t * (B_ * OUT_) + b * OUT_ + o] = 0.f;
    }

    int h = (slice << 6) + tid;
    const float* p = in_cur + b * H_ + h;
    float2* ckb = ckpt + b * H_ + h;   // [T_/8][B_][H_] layout
    float v = 0.f, cur = 0.f;
    int tc = T_;                       // first crossing step (T_ = none)
    float buf0[FB_], buf1[FB_];
    #pragma unroll
    for (int s = 0; s < FB_; ++s) buf0[s] = p[(size_t)s * (B_ * H_)];
    #pragma unroll
    for (int s = 0; s < FB_; ++s) buf1[s] = p[(size_t)(FB_ + s) * (B_ * H_)];

    for (int t0 = 0; t0 < T_; t0 += 2 * FB_) {
        #pragma unroll
        for (int s = 0; s < FB_; ++s) {
            if ((s & 7) == 0)          // static (unrolled): checkpoint @ t0+s
                ckb[(size_t)((t0 + s) >> 3) * (B_ * H_)] = make_float2(v, cur);
            float vd = fmaf(0.1f, cur - v, v);
            tc = (vd > 0.5f && tc == T_) ? (t0 + s) : tc;
            v = vd;
            cur = cur * 0.8f + buf0[s];
        }
        if (t0 + 2 * FB_ < T_) {
            #pragma unroll
            for (int s = 0; s < FB_; ++s)
                buf0[s] = p[(size_t)(t0 + 2 * FB_ + s) * (B_ * H_)];
        }
        #pragma unroll
        for (int s = 0; s < FB_; ++s) {
            if ((s & 7) == 0)          // checkpoint @ t0+FB_+s
                ckb[(size_t)((t0 + FB_ + s) >> 3) * (B_ * H_)] = make_float2(v, cur);
            float vd = fmaf(0.1f, cur - v, v);
            tc = (vd > 0.5f && tc == T_) ? (t0 + FB_ + s) : tc;
            v = vd;
            cur = cur * 0.8f + buf1[s];
        }
        if (t0 + 3 * FB_ < T_) {
            #pragma unroll
            for (int s = 0; s < FB_; ++s)
                buf1[s] = p[(size_t)(t0 + 3 * FB_ + s) * (B_ * H_)];
        }
    }
    if (tc < T_) atomicMin(&tfirst[b], (unsigned)tc);
}

// ---------------------------------------------------------------------------
// Exact completion for batches with a crossing (tfirst[b] < T_).
// Resume from checkpoint at c0 = tf & ~7 (batched loads, <= 7 steps), then
// exact per-step machinery for [tf, T_) with:
//   - depth-8 rotating NAMED-register inc pipeline (latency fully hidden,
//     no arrays -> no scratch; this was the 105us in R12)
//   - triple-buffered mword -> ONE barrier per step
// i_new = i_dec + input + z_prev @ w_rec.T ; y = z_new @ w_out.T.
// vo = io = 0 at entry (no output spikes before tf).
// ---------------------------------------------------------------------------
__global__ __launch_bounds__(512) void simfb_k(const unsigned* __restrict__ tfirst,
                                               const float* __restrict__ in_cur,
                                               const float2* __restrict__ ckpt,
                                               const float* __restrict__ w_rec_T,
                                               const float* __restrict__ w_out,
                                               float* __restrict__ out) {
    int b = blockIdx.x;
    unsigned tfu = tfirst[b];
    if (tfu >= (unsigned)T_) return;       // uniform early exit (before barriers)
    int tf = (int)tfu;
    int tid = threadIdx.x, wid = tid >> 6, lane = tid & 63;
    __shared__ unsigned long long mword[3][8];
    const size_t BH = B_ * H_;
    const float* icb = in_cur + b * H_ + tid;
    float* outp = out + b * OUT_ + tid;    // valid when tid < OUT_

    // ---- resume from checkpoint: <= 7 steps, loads batched into named regs
    int c0 = tf & ~7;
    float2 st = ckpt[(size_t)(c0 >> 3) * BH + b * H_ + tid];
    float v = st.x, cur = st.y;
#define PSTEP(X) { float vd_ = fmaf(0.1f, cur - v, v); v = vd_; cur = cur * 0.8f + (X); }
    {
        float j0 = icb[(size_t)min(c0 + 0, T_ - 1) * BH];
        float j1 = icb[(size_t)min(c0 + 1, T_ - 1) * BH];
        float j2 = icb[(size_t)min(c0 + 2, T_ - 1) * BH];
        float j3 = icb[(size_t)min(c0 + 3, T_ - 1) * BH];
        float j4 = icb[(size_t)min(c0 + 4, T_ - 1) * BH];
        float j5 = icb[(size_t)min(c0 + 5, T_ - 1) * BH];
        float j6 = icb[(size_t)min(c0 + 6, T_ - 1) * BH];
        int r = tf - c0;                   // 0..7 (wave-uniform)
        if (0 < r) PSTEP(j0)  if (1 < r) PSTEP(j1)  if (2 < r) PSTEP(j2)
        if (3 < r) PSTEP(j3)  if (4 < r) PSTEP(j4)  if (5 < r) PSTEP(j5)
        if (6 < r) PSTEP(j6)
    }
#undef PSTEP

    // ---- exact machinery for [tf, T_). vo = io = 0 at entry.
    float vo = 0.f, io = 0.f;
    if (tid < 24) ((unsigned long long*)mword)[tid] = 0ULL;  // all 3 slots
    // depth-8 inc pipeline prologue (named regs only)
    float i0 = icb[(size_t)min(tf + 0, T_ - 1) * BH];
    float i1 = icb[(size_t)min(tf + 1, T_ - 1) * BH];
    float i2 = icb[(size_t)min(tf + 2, T_ - 1) * BH];
    float i3 = icb[(size_t)min(tf + 3, T_ - 1) * BH];
    float i4 = icb[(size_t)min(tf + 4, T_ - 1) * BH];
    float i5 = icb[(size_t)min(tf + 5, T_ - 1) * BH];
    float i6 = icb[(size_t)min(tf + 6, T_ - 1) * BH];
    float i7 = icb[(size_t)min(tf + 7, T_ - 1) * BH];
    __syncthreads();                       // mword init visible
    int p = 0;                             // slot for step t; (t - tf) % 3
    for (int t = tf; t < T_; ++t) {
        float inc = i0;                    // issued >= 8 steps ago: complete
        i0 = i1; i1 = i2; i2 = i3; i3 = i4; i4 = i5; i5 = i6; i6 = i7;
        i7 = icb[(size_t)min(t + 8, T_ - 1) * BH];   // issue 8 ahead
        float vd = fmaf(0.1f, cur - v, v);
        bool z = vd > 0.5f;
        v = z ? 0.f : vd;
        unsigned long long bal = __ballot(z);
        if (lane == 0) mword[p][wid] = bal;
        __syncthreads();                   // the ONLY barrier per step
        int pprev = p == 0 ? 2 : p - 1;    // z_prev slot (zero at t == tf)
        float c2 = cur * 0.8f + inc;       // i_dec + input first
        for (int w = 0; w < 8; ++w) {      // + z_prev @ w_rec.T, ascending j
            unsigned long long mm = mword[pprev][w];
            while (mm) {
                int j = __builtin_ctzll(mm);
                c2 += w_rec_T[(size_t)((w << 6) + j) * H_ + tid];
                mm &= mm - 1;
            }
        }
        cur = c2;
        if (tid < OUT_) {
            float y = 0.f;
            for (int w = 0; w < 8; ++w) {  // z_new @ w_out.T
                unsigned long long mm = mword[p][w];
                while (mm) {
                    int j = __builtin_ctzll(mm);
                    y += w_out[tid * H_ + (w << 6) + j];
                    mm &= mm - 1;
                }
            }
            float von = fmaf(0.1f, io - vo, vo);   // uses OLD io
            io = io * 0.8f + y;
            outp[(size_t)t * (B_ * OUT_)] = von;
            vo = von;
        }
        // no trailing barrier: next write goes to slot (p+1)%3, disjoint from
        // this step's read slots pprev=(p-1)%3 and p.
        p = p == 2 ? 0 : p + 1;
    }
}

// ---------------------------------------------------------------------------
extern "C" void kernel_launch(void* const* d_in, const int* in_sizes, int n_in,
                              void* d_out, int out_size, void* d_ws, size_t ws_size,
                              hipStream_t stream) {
    const int*   x     = (const int*)d_in[0];
    const float* w_in  = (const float*)d_in[1];
    const float* w_rec = (const float*)d_in[2];
    const float* w_out = (const float*)d_in[3];
    float* out = (float*)d_out;

    char* ws = (char*)d_ws;
    size_t off = 0;
    int*      cnt     = (int*)(ws + off);      off += (size_t)B_ * T_ * 4;            // 32 KB
    unsigned* tfirst  = (unsigned*)(ws + off); off += (size_t)B_ * 4;                 // 128 B
    unsigned* data    = (unsigned*)(ws + off); off += (size_t)B_ * T_ * CAP_ * 4;     // 6 MB
    float*    w_in_T  = (float*)(ws + off);    off += (size_t)(IN_ + 1) * H_ * 4;     // 8 MB + zero row
    float*    w_rec_T = (float*)(ws + off);    off += (size_t)H_ * H_ * 4;            // 1 MB
    float*    in_cur  = (float*)(ws + off);    off += (size_t)T_ * B_ * H_ * 4;       // 16 MB
    float2*   ckpt    = (float2*)(ws + off);   off += (size_t)(T_ / 8) * B_ * H_ * 8; // 4 MB

    (void)hipMemsetAsync(cnt, 0, (size_t)B_ * T_ * 4, stream);
    (void)hipMemsetAsync(tfirst, 0xFF, (size_t)B_ * 4, stream);          // = huge
    (void)hipMemsetAsync(w_in_T + (size_t)IN_ * H_, 0, H_ * 4, stream);  // zero pad row

    // z=0: w_in transpose (128x16 tiles); z=1: w_rec (16x16); z=2: scatter (1024 blocks)
    prep_k<<<dim3(128, 16, 3), dim3(32, 8), 0, stream>>>(w_in, w_rec, (const int4*)x,
                                                         w_in_T, w_rec_T, cnt, data);

    incur_k<<<B_ * (T_ / Q_), 512, 0, stream>>>(cnt, data, w_in_T, in_cur);

    simfast_k<<<B_ * 8, 64, 0, stream>>>(in_cur, tfirst, ckpt, out);

    simfb_k<<<B_, 512, 0, stream>>>(tfirst, in_cur, ckpt, w_rec_T, w_out, out);
}

// Round 14
// 151.902 us; speedup vs baseline: 1.1481x; 1.0491x over previous
//
#include <hip/hip_runtime.h>

#define B_   32
#define S_   8192
#define T_   256
#define IN_  4096
#define H_   512
#define OUT_ 10
#define CAP_ 192   // max events per (b,t) bucket; max observed ~70 (Poisson(32))
#define Q_   4     // buckets per incur block
#define FB_  16    // steps per register buffer in simfast_k
#define PADC (CAP_ + 8)

// ---------------------------------------------------------------------------
// Fused prep: z=0 transpose w_in, z=1 transpose w_rec, z=2 event scatter.
// block = (32,8)
// ---------------------------------------------------------------------------
__global__ void prep_k(const float* __restrict__ w_in, const float* __restrict__ w_rec,
                       const int4* __restrict__ x,
                       float* __restrict__ w_in_T, float* __restrict__ w_rec_T,
                       int* __restrict__ cnt, unsigned* __restrict__ data) {
    int zz = blockIdx.z;
    int tx = threadIdx.x, ty = threadIdx.y;
    if (zz == 2) {
        // ---- scatter: key = (pos<<14)|(s<<1)|val; max key per pos = last event
        int flat = blockIdx.y * gridDim.x + blockIdx.x;
        if (flat >= (B_ * S_) / 256) return;
        int e = flat * 256 + ty * 32 + tx;
        int4 ev = x[e];                       // cx, cy, val, ts
        int b = e >> 13;                      // S_ = 8192
        int s = e & (S_ - 1);
        unsigned pos = (unsigned)(ev.x * ev.y);
        unsigned key = (pos << 14) | ((unsigned)s << 1) | (unsigned)ev.z;
        int bucket = b * T_ + ev.w;
        int slot = atomicAdd(&cnt[bucket], 1);
        if (slot < CAP_) data[bucket * CAP_ + slot] = key;
        return;
    }
    // ---- transpose src[R][C] -> dst[C][R]
    const float* src = zz ? w_rec : w_in;
    float* dst = zz ? w_rec_T : w_in_T;
    const int R = H_, C = zz ? H_ : IN_;
    int bx = blockIdx.x * 32, by = blockIdx.y * 32;
    if (bx >= C || by >= R) return;
    __shared__ float tile[32][33];
    #pragma unroll
    for (int k = 0; k < 32; k += 8) {
        int r = by + ty + k, c = bx + tx;
        if (r < R && c < C) tile[ty + k][tx] = src[(size_t)r * C + c];
    }
    __syncthreads();
    #pragma unroll
    for (int k = 0; k < 32; k += 8) {
        int c = bx + ty + k, r = by + tx;
        if (c < C && r < R) dst[(size_t)c * R + r] = tile[tx][ty + k];
    }
}

// ---------------------------------------------------------------------------
// Per-bucket dedup + input-current accumulation.
// Block = 512 threads = 4 buckets x 128 threads; thread owns 4 h (float4).
// plist pre-filled with IN_ (zero row) -> gather loop has NO clamps/selects.
// ---------------------------------------------------------------------------
__global__ __launch_bounds__(512) void incur_k(const int* __restrict__ cnt,
                                               const unsigned* __restrict__ data,
                                               const float* __restrict__ w_in_T,
                                               float* __restrict__ in_cur) {
    int b  = blockIdx.x / (T_ / Q_);
    int tg = (blockIdx.x % (T_ / Q_)) * Q_;           // first t of group
    __shared__ unsigned keys[Q_][PADC];
    __shared__ unsigned char wf[Q_][PADC];
    __shared__ unsigned short plist[Q_][PADC];
    __shared__ int mq[Q_];
    int tid = threadIdx.x;
    int q = tid >> 7, lt = tid & 127;
    int bucket = b * T_ + tg + q;
    int n = cnt[bucket]; if (n > CAP_) n = CAP_;
    for (int i = lt; i < n; i += 128) keys[q][i] = data[bucket * CAP_ + i];
    #pragma unroll
    for (int i = lt; i < PADC; i += 128) plist[q][i] = (unsigned short)IN_;  // zero-row pad
    if (lt == 0) mq[q] = 0;
    __syncthreads();
    // ---- winner flags (max key per pos, val==1), batched scans (no break)
    for (int i = lt; i < n; i += 128) {
        unsigned ki = keys[q][i], pi = ki >> 14;
        bool dead = false;
        for (int j = 0; j < n; j += 4) {
            unsigned a0 = keys[q][j];
            unsigned a1 = keys[q][j + 1 < n ? j + 1 : 0];
            unsigned a2 = keys[q][j + 2 < n ? j + 2 : 0];
            unsigned a3 = keys[q][j + 3 < n ? j + 3 : 0];
            dead |= (((a0 >> 14) == pi) & (a0 > ki));
            dead |= ((j + 1 < n) & ((a1 >> 14) == pi) & (a1 > ki));
            dead |= ((j + 2 < n) & ((a2 >> 14) == pi) & (a2 > ki));
            dead |= ((j + 3 < n) & ((a3 >> 14) == pi) & (a3 > ki));
        }
        wf[q][i] = (unsigned char)(((ki & 1u) != 0u) && !dead);
    }
    __syncthreads();
    // ---- rank by ascending key (winners have distinct pos) + compact
    for (int i = lt; i < n; i += 128) {
        if (wf[q][i]) {
            unsigned ki = keys[q][i];
            int r = 0;
            for (int j = 0; j < n; j += 4) {
                r += (int)(wf[q][j] && keys[q][j] < ki);
                r += (int)((j + 1 < n) && wf[q][j + 1] && keys[q][j + 1] < ki);
                r += (int)((j + 2 < n) && wf[q][j + 2] && keys[q][j + 2] < ki);
                r += (int)((j + 3 < n) && wf[q][j + 3] && keys[q][j + 3] < ki);
            }
            plist[q][r] = (unsigned short)(ki >> 14);
            atomicAdd(&mq[q], 1);
        }
    }
    __syncthreads();                                  // plist + mq ready
    // ---- gather: thread sums rows for h = lt*4 .. lt*4+3 (float4)
    int m = mq[q];
    const float4* w4 = (const float4*)w_in_T;         // [IN_+1][128]
    float4 acc = make_float4(0.f, 0.f, 0.f, 0.f);
    for (int k = 0; k < m; k += 4) {                  // pads read the zero row
        float4 g0 = w4[(size_t)plist[q][k + 0] * 128 + lt];
        float4 g1 = w4[(size_t)plist[q][k + 1] * 128 + lt];
        float4 g2 = w4[(size_t)plist[q][k + 2] * 128 + lt];
        float4 g3 = w4[(size_t)plist[q][k + 3] * 128 + lt];
        acc.x = (((acc.x + g0.x) + g1.x) + g2.x) + g3.x;
        acc.y = (((acc.y + g0.y) + g1.y) + g2.y) + g3.y;
        acc.z = (((acc.z + g0.z) + g1.z) + g2.z) + g3.z;
        acc.w = (((acc.w + g0.w) + g1.w) + g2.w) + g3.w;
    }
    ((float4*)(in_cur + (size_t)(tg + q) * (B_ * H_) + b * H_))[lt] = acc;
}

// ---------------------------------------------------------------------------
// Fast spike scan: 256 blocks x 64 threads (one wave per CU chip-wide).
// Thread = unit (b, h). Walks the no-reset trajectory (bit-identical to the
// true one up to the first crossing), records the EXACT first crossing step
// via atomicMin(tfirst[b]), checkpoints (v, cur) every 8 steps (state at the
// START of step t, exact for all t <= first crossing), zero-fills out.
// ---------------------------------------------------------------------------
__global__ __launch_bounds__(64) void simfast_k(const float* __restrict__ in_cur,
                                                unsigned* __restrict__ tfirst,
                                                float2* __restrict__ ckpt,
                                                float* __restrict__ out) {
    int blk = blockIdx.x;              // B_*8 blocks
    int b = blk >> 3;
    int slice = blk & 7;
    int tid = threadIdx.x;

    // zero this block's out slice: t in [slice*32, slice*32+32), 10 outs
    #pragma unroll
    for (int i = tid; i < 320; i += 64) {
        int t = (slice << 5) + i / 10;
        int o = i - (i / 10) * 10;
        out[(size_t)t * (B_ * OUT_) + b * OUT_ + o] = 0.f;
    }

    int h = (slice << 6) + tid;
    const float* p = in_cur + b * H_ + h;
    float2* ckb = ckpt + b * H_ + h;   // [T_/8][B_][H_] layout
    float v = 0.f, cur = 0.f;
    int tc = T_;                       // first crossing step (T_ = none)
    float buf0[FB_], buf1[FB_];
    #pragma unroll
    for (int s = 0; s < FB_; ++s) buf0[s] = p[(size_t)s * (B_ * H_)];
    #pragma unroll
    for (int s = 0; s < FB_; ++s) buf1[s] = p[(size_t)(FB_ + s) * (B_ * H_)];

    for (int t0 = 0; t0 < T_; t0 += 2 * FB_) {
        #pragma unroll
        for (int s = 0; s < FB_; ++s) {
            if ((s & 7) == 0)          // static (unrolled): checkpoint @ t0+s
                ckb[(size_t)((t0 + s) >> 3) * (B_ * H_)] = make_float2(v, cur);
            float vd = fmaf(0.1f, cur - v, v);
            tc = (vd > 0.5f && tc == T_) ? (t0 + s) : tc;
            v = vd;
            cur = cur * 0.8f + buf0[s];
        }
        if (t0 + 2 * FB_ < T_) {
            #pragma unroll
            for (int s = 0; s < FB_; ++s)
                buf0[s] = p[(size_t)(t0 + 2 * FB_ + s) * (B_ * H_)];
        }
        #pragma unroll
        for (int s = 0; s < FB_; ++s) {
            if ((s & 7) == 0)          // checkpoint @ t0+FB_+s
                ckb[(size_t)((t0 + FB_ + s) >> 3) * (B_ * H_)] = make_float2(v, cur);
            float vd = fmaf(0.1f, cur - v, v);
            tc = (vd > 0.5f && tc == T_) ? (t0 + FB_ + s) : tc;
            v = vd;
            cur = cur * 0.8f + buf1[s];
        }
        if (t0 + 3 * FB_ < T_) {
            #pragma unroll
            for (int s = 0; s < FB_; ++s)
                buf1[s] = p[(size_t)(t0 + 3 * FB_ + s) * (B_ * H_)];
        }
    }
    if (tc < T_) atomicMin(&tfirst[b], (unsigned)tc);
}

// ---------------------------------------------------------------------------
// Exact completion for batches with an OUTPUT-RELEVANT crossing.
// KEY: a spike at step t feeds y(t) -> io(t) -> out[t+1]. A spike at the
// FINAL step (t = T_-1) can never reach the output. So tf >= T_-1 requires
// no work at all (out is already the correct all-zero trajectory, written by
// simfast). R6's ground-truth full walk (absmax 0.0) proved this data's only
// crossings are at t = 255, so this exit is the hot path.
// General path (tf < T_-1) retained for correctness on arbitrary inputs:
// ckpt resume + per-step ballot/LDS machinery with z_prev timing.
// ---------------------------------------------------------------------------
__global__ __launch_bounds__(512) void simfb_k(const unsigned* __restrict__ tfirst,
                                               const float* __restrict__ in_cur,
                                               const float2* __restrict__ ckpt,
                                               const float* __restrict__ w_rec_T,
                                               const float* __restrict__ w_out,
                                               float* __restrict__ out) {
    int b = blockIdx.x;
    unsigned tfu = tfirst[b];
    if (tfu >= (unsigned)(T_ - 1)) return;  // no crossing, or final-step-only:
                                            // output provably unaffected.
    int tf = (int)tfu;
    int tid = threadIdx.x, wid = tid >> 6, lane = tid & 63;
    __shared__ unsigned long long mword[3][8];
    const size_t BH = B_ * H_;
    const float* icb = in_cur + b * H_ + tid;
    float* outp = out + b * OUT_ + tid;    // valid when tid < OUT_

    // ---- resume from checkpoint: <= 7 steps, loads batched into named regs
    int c0 = tf & ~7;
    float2 st = ckpt[(size_t)(c0 >> 3) * BH + b * H_ + tid];
    float v = st.x, cur = st.y;
#define PSTEP(X) { float vd_ = fmaf(0.1f, cur - v, v); v = vd_; cur = cur * 0.8f + (X); }
    {
        float j0 = icb[(size_t)min(c0 + 0, T_ - 1) * BH];
        float j1 = icb[(size_t)min(c0 + 1, T_ - 1) * BH];
        float j2 = icb[(size_t)min(c0 + 2, T_ - 1) * BH];
        float j3 = icb[(size_t)min(c0 + 3, T_ - 1) * BH];
        float j4 = icb[(size_t)min(c0 + 4, T_ - 1) * BH];
        float j5 = icb[(size_t)min(c0 + 5, T_ - 1) * BH];
        float j6 = icb[(size_t)min(c0 + 6, T_ - 1) * BH];
        int r = tf - c0;                   // 0..7 (wave-uniform)
        if (0 < r) PSTEP(j0)  if (1 < r) PSTEP(j1)  if (2 < r) PSTEP(j2)
        if (3 < r) PSTEP(j3)  if (4 < r) PSTEP(j4)  if (5 < r) PSTEP(j5)
        if (6 < r) PSTEP(j6)
    }
#undef PSTEP

    // ---- exact machinery for [tf, T_). vo = io = 0 at entry.
    float vo = 0.f, io = 0.f;
    if (tid < 24) ((unsigned long long*)mword)[tid] = 0ULL;  // all 3 slots
    __syncthreads();                       // mword init visible
    int p = 0;                             // slot for step t; (t - tf) % 3
    for (int t = tf; t < T_; ++t) {
        float inc = icb[(size_t)t * BH];
        float vd = fmaf(0.1f, cur - v, v);
        bool z = vd > 0.5f;
        v = z ? 0.f : vd;
        unsigned long long bal = __ballot(z);
        if (lane == 0) mword[p][wid] = bal;
        __syncthreads();                   // the ONLY barrier per step
        int pprev = p == 0 ? 2 : p - 1;    // z_prev slot (zero at t == tf)
        float c2 = cur * 0.8f + inc;       // i_dec + input first
        for (int w = 0; w < 8; ++w) {      // + z_prev @ w_rec.T, ascending j
            unsigned long long mm = mword[pprev][w];
            while (mm) {
                int j = __builtin_ctzll(mm);
                c2 += w_rec_T[(size_t)((w << 6) + j) * H_ + tid];
                mm &= mm - 1;
            }
        }
        cur = c2;
        if (tid < OUT_) {
            float y = 0.f;
            for (int w = 0; w < 8; ++w) {  // z_new @ w_out.T
                unsigned long long mm = mword[p][w];
                while (mm) {
                    int j = __builtin_ctzll(mm);
                    y += w_out[tid * H_ + (w << 6) + j];
                    mm &= mm - 1;
                }
            }
            float von = fmaf(0.1f, io - vo, vo);   // uses OLD io
            io = io * 0.8f + y;
            outp[(size_t)t * (B_ * OUT_)] = von;
            vo = von;
        }
        // no trailing barrier: next write goes to slot (p+1)%3, disjoint from
        // this step's read slots pprev=(p-1)%3 and p.
        p = p == 2 ? 0 : p + 1;
    }
}

// ---------------------------------------------------------------------------
extern "C" void kernel_launch(void* const* d_in, const int* in_sizes, int n_in,
                              void* d_out, int out_size, void* d_ws, size_t ws_size,
                              hipStream_t stream) {
    const int*   x     = (const int*)d_in[0];
    const float* w_in  = (const float*)d_in[1];
    const float* w_rec = (const float*)d_in[2];
    const float* w_out = (const float*)d_in[3];
    float* out = (float*)d_out;

    char* ws = (char*)d_ws;
    size_t off = 0;
    int*      cnt     = (int*)(ws + off);      off += (size_t)B_ * T_ * 4;            // 32 KB
    unsigned* tfirst  = (unsigned*)(ws + off); off += (size_t)B_ * 4;                 // 128 B
    unsigned* data    = (unsigned*)(ws + off); off += (size_t)B_ * T_ * CAP_ * 4;     // 6 MB
    float*    w_in_T  = (float*)(ws + off);    off += (size_t)(IN_ + 1) * H_ * 4;     // 8 MB + zero row
    float*    w_rec_T = (float*)(ws + off);    off += (size_t)H_ * H_ * 4;            // 1 MB
    float*    in_cur  = (float*)(ws + off);    off += (size_t)T_ * B_ * H_ * 4;       // 16 MB
    float2*   ckpt    = (float2*)(ws + off);   off += (size_t)(T_ / 8) * B_ * H_ * 8; // 4 MB

    (void)hipMemsetAsync(cnt, 0, (size_t)B_ * T_ * 4, stream);
    (void)hipMemsetAsync(tfirst, 0xFF, (size_t)B_ * 4, stream);          // = huge
    (void)hipMemsetAsync(w_in_T + (size_t)IN_ * H_, 0, H_ * 4, stream);  // zero pad row

    // z=0: w_in transpose (128x16 tiles); z=1: w_rec (16x16); z=2: scatter (1024 blocks)
    prep_k<<<dim3(128, 16, 3), dim3(32, 8), 0, stream>>>(w_in, w_rec, (const int4*)x,
                                                         w_in_T, w_rec_T, cnt, data);

    incur_k<<<B_ * (T_ / Q_), 512, 0, stream>>>(cnt, data, w_in_T, in_cur);

    simfast_k<<<B_ * 8, 64, 0, stream>>>(in_cur, tfirst, ckpt, out);

    simfb_k<<<B_, 512, 0, stream>>>(tfirst, in_cur, ckpt, w_rec_T, w_out, out);
}